// Round 1
// 549.449 us; speedup vs baseline: 1.0132x; 1.0132x over previous
//
#include <hip/hip_runtime.h>

#define NA 50000
#define NB 50000
#define NN 50000
#define CDIM 128
#define EDGES 800000
#define SS 8
#define INDIM 64
#define HDIM 64
#define NBASES 8
#define NBUCK 98
#define BSH 9

typedef __attribute__((ext_vector_type(8))) short bf16x8;
typedef __attribute__((ext_vector_type(4))) float f32x4;

// ---------------------------------------------------------------------------
// Workspace layout (4-byte element offsets):
//   0         col      [3*E]        int
//   2400000   rowptr   [3*(NN+1)]   int
//   2550016   buf      [3*E]        uint
//   4950016   bcnt     [3*98]       int      (pad 304)
//   4950320   boff     [3*99]       int      (pad 304)
//   4950624   bcur     [3*98]       int      (pad 304)
//   4950928   xa_buf   [NA*128]     float
//   11350928  xb_buf   [NB*128]     float
//   17750928  Wbf      ushort[6*128*128]  (bf16, row-major [j][k])
//   17800080  coeffs   [3*8]        float  (pad to 17800112)
//   17800112  xa_bf0   ushort[(NN+1)*128]   (row NN = zero row)
//   21000176  xb_bf0   ushort[(NN+1)*128]
//   24200240  xa_bf1   ushort[(NN+1)*128]
//   27400304  xb_bf1   ushort[(NN+1)*128]
//   30600368  end (~122 MB)
// ---------------------------------------------------------------------------

__device__ __forceinline__ unsigned short f2bf(float f) {
    unsigned u = __float_as_uint(f);
    return (unsigned short)((u + 0x7FFFu + ((u >> 16) & 1u)) >> 16);
}

// Schema GCN + coefficient computation. One block, 512 threads.
__global__ __launch_bounds__(512) void schema_kernel(
    const float* __restrict__ schema_x, const int* __restrict__ sei,
    const float* __restrict__ preW, const float* __restrict__ preb,
    const float* __restrict__ gcnW, const float* __restrict__ gcnb,
    const float* __restrict__ coW, const float* __restrict__ cob,
    float* __restrict__ out_sf, float* __restrict__ out_ori,
    float* __restrict__ coeffs)
{
    __shared__ float h[SS][HDIM];
    __shared__ float xw[SS][HDIM];
    __shared__ float sf[SS][HDIM];
    __shared__ float deg[SS];
    __shared__ float nrm[32];
    __shared__ int es[32], ed[32];

    int t = threadIdx.x;
    int i = t >> 6, j = t & 63;

    float acc = preb[j];
    for (int k = 0; k < INDIM; k++) acc += schema_x[i * INDIM + k] * preW[j * INDIM + k];
    h[i][j] = acc;
    out_ori[i * HDIM + j] = acc;
    if (t < SS) deg[t] = 0.0f;
    __syncthreads();

    if (t < 32) {
        int s, d;
        if (t < 24) { s = sei[t]; d = sei[24 + t]; }
        else        { s = t - 24; d = t - 24; }
        es[t] = s; ed[t] = d;
        atomicAdd(&deg[d], 1.0f);
    }
    __syncthreads();
    if (t < 32) {
        nrm[t] = rsqrtf(fmaxf(deg[es[t]], 1e-12f)) * rsqrtf(fmaxf(deg[ed[t]], 1e-12f));
    }
    float a2 = 0.0f;
    for (int k = 0; k < HDIM; k++) a2 += h[i][k] * gcnW[j * HDIM + k];
    xw[i][j] = a2;
    __syncthreads();

    float o = gcnb[j];
    for (int e = 0; e < 32; e++) {
        if (ed[e] == i) o += xw[es[e]][j] * nrm[e];
    }
    float s = fmaxf(o, 0.0f);
    sf[i][j] = s;
    out_sf[i * HDIM + j] = s;
    __syncthreads();

    if (t < 24) {
        int ty = t >> 3, ii = t & 7;
        int srow = (ty == 1) ? 1 : 0;
        int drow = (ty == 0) ? 1 : 0;
        float a = cob[ii];
        for (int k = 0; k < HDIM; k++) a += sf[srow][k] * coW[ii * (2 * HDIM) + k];
        for (int k = 0; k < HDIM; k++) a += sf[drow][k] * coW[ii * (2 * HDIM) + HDIM + k];
        coeffs[ty * 8 + ii] = a;
    }
}

// W in bf16, row-major [mat][j][k] (B-operand needs contiguous k per row)
__global__ __launch_bounds__(256) void build_w_kernel(
    const float* __restrict__ bases, const float* __restrict__ coeffs,
    unsigned short* __restrict__ Wbf)
{
    int idx = blockIdx.x * blockDim.x + threadIdx.x;   // < 6*16384
    int lt = idx >> 14;
    int jk = idx & 16383;
    int l = lt / 3, ty = lt % 3;
    float acc = 0.0f;
#pragma unroll
    for (int i = 0; i < NBASES; i++)
        acc += coeffs[ty * 8 + i] * bases[((size_t)(l * NBASES + i) << 14) + jk];
    Wbf[idx] = f2bf(acc);
}

__global__ __launch_bounds__(256) void tobf16_kernel(
    const float* __restrict__ in, unsigned short* __restrict__ out, int n)
{
    int i = (blockIdx.x * 256 + threadIdx.x) * 4;
    if (i >= n) return;
    float4 f = *(const float4*)(in + i);
    ushort4 o;
    o.x = f2bf(f.x); o.y = f2bf(f.y); o.z = f2bf(f.z); o.w = f2bf(f.w);
    *(ushort4*)(out + i) = o;
}

__global__ __launch_bounds__(256) void zero_rows_kernel(
    unsigned short* a0, unsigned short* b0, unsigned short* a1, unsigned short* b1)
{
    int t = threadIdx.x;
    int tab = t >> 6, w = t & 63;
    unsigned short* p = (tab == 0) ? a0 : (tab == 1) ? b0 : (tab == 2) ? a1 : b1;
    ((unsigned*)(p + (size_t)NN * CDIM))[w] = 0u;
}

// ---------------- locality-aware CSR build ----------------------------------

__global__ __launch_bounds__(256) void bucket_count_kernel(
    const int* __restrict__ ab, const int* __restrict__ ba,
    const int* __restrict__ aa, int* __restrict__ bcnt)
{
    __shared__ int h[NBUCK];
    int t = threadIdx.x;
    int ty = blockIdx.y;
    const int* ei = (ty == 0) ? ab : (ty == 1) ? ba : aa;
    if (t < NBUCK) h[t] = 0;
    __syncthreads();
    int cb = blockIdx.x * 4096;
    int en = min(cb + 4096, EDGES);
    for (int e = cb + t; e < en; e += 256)
        atomicAdd(&h[ei[EDGES + e] >> BSH], 1);
    __syncthreads();
    if (t < NBUCK) atomicAdd(&bcnt[ty * NBUCK + t], h[t]);
}

__global__ __launch_bounds__(32) void bucket_scan_kernel(
    const int* __restrict__ bcnt, int* __restrict__ boff, int* __restrict__ bcur)
{
    int t = threadIdx.x;
    if (t < 3) {
        int run = 0;
        for (int i = 0; i < NBUCK; i++) {
            int c = bcnt[t * NBUCK + i];
            boff[t * (NBUCK + 1) + i] = run;
            bcur[t * NBUCK + i] = run;
            run += c;
        }
        boff[t * (NBUCK + 1) + NBUCK] = run;
    }
}

__global__ __launch_bounds__(256) void bucket_partition_kernel(
    const int* __restrict__ ab, const int* __restrict__ ba,
    const int* __restrict__ aa, int* __restrict__ bcur,
    unsigned* __restrict__ buf)
{
    __shared__ int h[NBUCK];
    __shared__ int basearr[NBUCK];
    __shared__ int cur[NBUCK];
    int t = threadIdx.x;
    int ty = blockIdx.y;
    const int* ei = (ty == 0) ? ab : (ty == 1) ? ba : aa;
    if (t < NBUCK) h[t] = 0;
    __syncthreads();
    int cb = blockIdx.x * 4096;
    int en = min(cb + 4096, EDGES);
    for (int e = cb + t; e < en; e += 256)
        atomicAdd(&h[ei[EDGES + e] >> BSH], 1);
    __syncthreads();
    if (t < NBUCK) {
        basearr[t] = atomicAdd(&bcur[ty * NBUCK + t], h[t]);
        cur[t] = 0;
    }
    __syncthreads();
    for (int e = cb + t; e < en; e += 256) {
        int src = ei[e], dst = ei[EDGES + e];
        int b = dst >> BSH;
        int r = atomicAdd(&cur[b], 1);
        buf[(size_t)ty * EDGES + basearr[b] + r] =
            ((unsigned)(dst & 511) << 16) | (unsigned)src;
    }
}

__global__ __launch_bounds__(256) void bucket_scatter_kernel(
    const unsigned* __restrict__ buf, const int* __restrict__ boff,
    int* __restrict__ rowptr, int* __restrict__ col)
{
    __shared__ int cnt[512];
    __shared__ int part[256];
    int t = threadIdx.x;
    int b = blockIdx.x, ty = blockIdx.y;
    int nstart = boff[ty * (NBUCK + 1) + b];
    int nend   = boff[ty * (NBUCK + 1) + b + 1];
    int n = nend - nstart;
    cnt[t] = 0; cnt[t + 256] = 0;
    __syncthreads();
    const unsigned* bb = buf + (size_t)ty * EDGES + nstart;
    for (int i = t; i < n; i += 256)
        atomicAdd(&cnt[bb[i] >> 16], 1);
    __syncthreads();
    int a0 = cnt[2 * t], a1 = cnt[2 * t + 1];
    int s = a0 + a1;
    part[t] = s;
    __syncthreads();
    for (int off = 1; off < 256; off <<= 1) {
        int v = (t >= off) ? part[t - off] : 0;
        __syncthreads();
        part[t] += v;
        __syncthreads();
    }
    int excl = part[t] - s;
    int p0 = excl, p1 = excl + a0;
    cnt[2 * t] = p0; cnt[2 * t + 1] = p1;
    int row0 = (b << BSH) + 2 * t;
    int rbase = ty * (NN + 1);
    if (row0 < NN)     rowptr[rbase + row0] = nstart + p0;
    if (row0 + 1 < NN) rowptr[rbase + row0 + 1] = nstart + p1;
    if (b == NBUCK - 1 && t == 255) rowptr[rbase + NN] = EDGES;
    __syncthreads();
    int* cc = col + (size_t)ty * EDGES + nstart;
    for (int i = t; i < n; i += 256) {
        unsigned pk = bb[i];
        int r = atomicAdd(&cnt[pk >> 16], 1);
        cc[r] = (int)(pk & 0xFFFFu);
    }
}

// ---------------- fused gather + MFMA matmul + LN -> ReLU -------------------

__device__ __forceinline__ float4 gather2_bf(
    const unsigned short* __restrict__ xsrc, const int* __restrict__ col,
    int s, int e, int half, int off)
{
    float4 g = {0.f, 0.f, 0.f, 0.f};
    int n = e - s;
    if (n > 0) {
        if (n <= 16) {
            // fast path: ~57% of rows (Poisson(16) degrees) need only 8 slots/half
            int cs[8];
#pragma unroll
            for (int j = 0; j < 8; j++) {
                int slot = s + 2 * j + half;
                int cc = col[min(slot, e - 1)];
                cs[j] = (slot < e) ? cc : NN;
            }
            uint2 v[8];
#pragma unroll
            for (int j = 0; j < 8; j++)
                v[j] = *(const uint2*)(xsrc + (size_t)cs[j] * CDIM + off);
#pragma unroll
            for (int j = 0; j < 8; j++) {
                g.x += __uint_as_float(v[j].x << 16);
                g.y += __uint_as_float(v[j].x & 0xffff0000u);
                g.z += __uint_as_float(v[j].y << 16);
                g.w += __uint_as_float(v[j].y & 0xffff0000u);
            }
        } else {
            int cs[16];
#pragma unroll
            for (int j = 0; j < 16; j++) {
                int slot = s + 2 * j + half;
                int cc = col[min(slot, e - 1)];
                cs[j] = (slot < e) ? cc : NN;
            }
            uint2 v[16];
#pragma unroll
            for (int j = 0; j < 16; j++)
                v[j] = *(const uint2*)(xsrc + (size_t)cs[j] * CDIM + off);
#pragma unroll
            for (int j = 0; j < 16; j++) {
                g.x += __uint_as_float(v[j].x << 16);
                g.y += __uint_as_float(v[j].x & 0xffff0000u);
                g.z += __uint_as_float(v[j].y << 16);
                g.w += __uint_as_float(v[j].y & 0xffff0000u);
            }
            for (int b2 = s + 32; b2 < e; b2 += 16) {
#pragma unroll
                for (int j = 0; j < 8; j++) {
                    int slot = b2 + 2 * j + half;
                    int cc = col[min(slot, e - 1)];
                    int id = (slot < e) ? cc : NN;
                    uint2 vv = *(const uint2*)(xsrc + (size_t)id * CDIM + off);
                    g.x += __uint_as_float(vv.x << 16);
                    g.y += __uint_as_float(vv.x & 0xffff0000u);
                    g.z += __uint_as_float(vv.y << 16);
                    g.w += __uint_as_float(vv.y & 0xffff0000u);
                }
            }
        }
    }
    g.x += __shfl_xor(g.x, 32, 64);
    g.y += __shfl_xor(g.y, 32, 64);
    g.z += __shfl_xor(g.z, 32, 64);
    g.w += __shfl_xor(g.w, 32, 64);
    return g;
}

#define RROWS 32
#define USTR 136   // ushort stride (pad) for bf16 U/V tiles
#define SSTR 129   // float stride for acc staging

// b-side: mean(bf x_a) + x_b -> bf16 U; U @ W^T (MFMA) + bias -> LN -> ReLU
// LDS: stage (used after MFMA) unioned with Ubf (used before) -> 16.5 KB/block
// -> 8 blocks/CU (wave cap) instead of 4 (was 25 KB separate).
__global__ __launch_bounds__(256, 8) void fuse_b_kernel(
    const unsigned short* __restrict__ xsrc, const float* __restrict__ xdst,
    const int* __restrict__ rowptr, const int* __restrict__ col,
    const unsigned short* __restrict__ Wbf, const float* __restrict__ bias,
    const float* __restrict__ lnw, const float* __restrict__ lnb,
    float* __restrict__ xnext, unsigned short* __restrict__ xnext_bf)
{
    __shared__ float4 smraw[1032];   // max(RROWS*USTR*2, RROWS*SSTR*4) = 16512 B
    unsigned short* Ubf = (unsigned short*)smraw;
    float* stage = (float*)smraw;
    int t = threadIdx.x;
    int base = blockIdx.x * RROWS;
    int wv = t >> 6;
    int lane = t & 63;
    int half = lane >> 5, cl = lane & 31;
    int off = cl << 2;

    for (int rr = 0; rr < RROWS / 4; rr++) {
        int r = rr * 4 + wv;
        int row = base + r;
        if (row < NN) {
            int s = rowptr[row], e = rowptr[row + 1];
            float4 g = gather2_bf(xsrc, col, s, e, half, off);
            if (half == 0) {
                float inv = 1.0f / (float)max(e - s, 1);
                const float4 xv = *(const float4*)(xdst + (size_t)row * CDIM + off);
                ushort4 o;
                o.x = f2bf(g.x * inv + xv.x);
                o.y = f2bf(g.y * inv + xv.y);
                o.z = f2bf(g.z * inv + xv.z);
                o.w = f2bf(g.w * inv + xv.w);
                *(ushort4*)&Ubf[r * USTR + off] = o;
            }
        } else if (half == 0) {
            *(ushort4*)&Ubf[r * USTR + off] = make_ushort4(0, 0, 0, 0);
        }
    }
    __syncthreads();

    // MFMA: wave wv -> N-tiles {2wv, 2wv+1}, M-tiles {0,1}
    int qd = lane >> 4;
    int ln16 = lane & 15;
    f32x4 acc00 = {0.f,0.f,0.f,0.f}, acc01 = acc00, acc10 = acc00, acc11 = acc00;
#pragma unroll
    for (int ks = 0; ks < 4; ks++) {
        int koff = ks * 32 + qd * 8;
        bf16x8 a0 = *(const bf16x8*)&Ubf[(ln16) * USTR + koff];
        bf16x8 a1 = *(const bf16x8*)&Ubf[(16 + ln16) * USTR + koff];
        bf16x8 b0 = *(const bf16x8*)&Wbf[(size_t)((2 * wv + 0) * 16 + ln16) * CDIM + koff];
        bf16x8 b1 = *(const bf16x8*)&Wbf[(size_t)((2 * wv + 1) * 16 + ln16) * CDIM + koff];
        acc00 = __builtin_amdgcn_mfma_f32_16x16x32_bf16(a0, b0, acc00, 0, 0, 0);
        acc01 = __builtin_amdgcn_mfma_f32_16x16x32_bf16(a0, b1, acc01, 0, 0, 0);
        acc10 = __builtin_amdgcn_mfma_f32_16x16x32_bf16(a1, b0, acc10, 0, 0, 0);
        acc11 = __builtin_amdgcn_mfma_f32_16x16x32_bf16(a1, b1, acc11, 0, 0, 0);
    }
    __syncthreads();   // all MFMA reads of Ubf done before stage overwrites it
    // C/D layout: col = lane&15 (in tile), row = quad*4 + reg
    {
        int c0 = (2 * wv + 0) * 16 + ln16;
        int c1 = (2 * wv + 1) * 16 + ln16;
#pragma unroll
        for (int i = 0; i < 4; i++) {
            int r0 = qd * 4 + i;
            stage[r0 * SSTR + c0] = acc00[i];
            stage[r0 * SSTR + c1] = acc01[i];
            stage[(16 + r0) * SSTR + c0] = acc10[i];
            stage[(16 + r0) * SSTR + c1] = acc11[i];
        }
    }
    __syncthreads();

    float b0v = bias[lane], b1v = bias[lane + 64];
    float lw0 = lnw[lane], lw1 = lnw[lane + 64];
    float lb0 = lnb[lane], lb1 = lnb[lane + 64];
    for (int rr = 0; rr < RROWS / 4; rr++) {
        int r = rr * 4 + wv;
        int row = base + r;
        if (row >= NN) continue;
        float v0 = stage[r * SSTR + lane] + b0v;
        float v1 = stage[r * SSTR + lane + 64] + b1v;
        float s = v0 + v1, s2 = v0 * v0 + v1 * v1;
#pragma unroll
        for (int o2 = 32; o2 > 0; o2 >>= 1) {
            s  += __shfl_xor(s,  o2, 64);
            s2 += __shfl_xor(s2, o2, 64);
        }
        float mu = s * (1.0f / CDIM);
        float var = s2 * (1.0f / CDIM) - mu * mu;
        float rs = rsqrtf(var + 1e-5f);
        float o0 = fmaxf((v0 - mu) * rs * lw0 + lb0, 0.0f);
        float o1 = fmaxf((v1 - mu) * rs * lw1 + lb1, 0.0f);
        size_t oi = (size_t)row * CDIM;
        xnext[oi + lane] = o0;
        xnext[oi + lane + 64] = o1;
        if (xnext_bf) {
            xnext_bf[oi + lane] = f2bf(o0);
            xnext_bf[oi + lane + 64] = f2bf(o1);
        }
    }
}

// a-side: U = mean_ba(bf x_b)+x_a, V = mean_aa(bf x_a)+x_a;
// out = U@W1^T + V@W2^T + b1 + b2 (MFMA) -> LN -> ReLU
// LDS: stage unioned with Ubf+Vbf -> 17.4 KB/block -> 8 blocks/CU (was 34 KB -> 4).
__global__ __launch_bounds__(256, 8) void fuse_a_kernel(
    const unsigned short* __restrict__ xsrc1, const int* __restrict__ rowptr1, const int* __restrict__ col1,
    const unsigned short* __restrict__ xsrc2, const int* __restrict__ rowptr2, const int* __restrict__ col2,
    const float* __restrict__ xdst,
    const unsigned short* __restrict__ W1bf, const unsigned short* __restrict__ W2bf,
    const float* __restrict__ bias1, const float* __restrict__ bias2,
    const float* __restrict__ lnw, const float* __restrict__ lnb,
    float* __restrict__ xnext, unsigned short* __restrict__ xnext_bf)
{
    __shared__ float4 smraw[1088];   // max(2*RROWS*USTR*2, RROWS*SSTR*4) = 17408 B
    unsigned short* Ubf = (unsigned short*)smraw;
    unsigned short* Vbf = Ubf + RROWS * USTR;
    float* stage = (float*)smraw;
    int t = threadIdx.x;
    int base = blockIdx.x * RROWS;
    int wv = t >> 6;
    int lane = t & 63;
    int half = lane >> 5, cl = lane & 31;
    int off = cl << 2;

    for (int rr = 0; rr < RROWS / 4; rr++) {
        int r = rr * 4 + wv;
        int row = base + r;
        if (row < NN) {
            int s1 = rowptr1[row], e1 = rowptr1[row + 1];
            float4 g1 = gather2_bf(xsrc1, col1, s1, e1, half, off);
            int s2 = rowptr2[row], e2 = rowptr2[row + 1];
            float4 g2 = gather2_bf(xsrc2, col2, s2, e2, half, off);
            if (half == 0) {
                const float4 xv = *(const float4*)(xdst + (size_t)row * CDIM + off);
                float i1 = 1.0f / (float)max(e1 - s1, 1);
                float i2 = 1.0f / (float)max(e2 - s2, 1);
                ushort4 ou, ov;
                ou.x = f2bf(g1.x * i1 + xv.x); ou.y = f2bf(g1.y * i1 + xv.y);
                ou.z = f2bf(g1.z * i1 + xv.z); ou.w = f2bf(g1.w * i1 + xv.w);
                ov.x = f2bf(g2.x * i2 + xv.x); ov.y = f2bf(g2.y * i2 + xv.y);
                ov.z = f2bf(g2.z * i2 + xv.z); ov.w = f2bf(g2.w * i2 + xv.w);
                *(ushort4*)&Ubf[r * USTR + off] = ou;
                *(ushort4*)&Vbf[r * USTR + off] = ov;
            }
        } else if (half == 0) {
            *(ushort4*)&Ubf[r * USTR + off] = make_ushort4(0, 0, 0, 0);
            *(ushort4*)&Vbf[r * USTR + off] = make_ushort4(0, 0, 0, 0);
        }
    }
    __syncthreads();

    int qd = lane >> 4;
    int ln16 = lane & 15;
    f32x4 acc00 = {0.f,0.f,0.f,0.f}, acc01 = acc00, acc10 = acc00, acc11 = acc00;
#pragma unroll
    for (int ks = 0; ks < 4; ks++) {
        int koff = ks * 32 + qd * 8;
        bf16x8 aU0 = *(const bf16x8*)&Ubf[(ln16) * USTR + koff];
        bf16x8 aU1 = *(const bf16x8*)&Ubf[(16 + ln16) * USTR + koff];
        bf16x8 aV0 = *(const bf16x8*)&Vbf[(ln16) * USTR + koff];
        bf16x8 aV1 = *(const bf16x8*)&Vbf[(16 + ln16) * USTR + koff];
        size_t wrow0 = (size_t)((2 * wv + 0) * 16 + ln16) * CDIM + koff;
        size_t wrow1 = (size_t)((2 * wv + 1) * 16 + ln16) * CDIM + koff;
        bf16x8 b10 = *(const bf16x8*)&W1bf[wrow0];
        bf16x8 b11 = *(const bf16x8*)&W1bf[wrow1];
        bf16x8 b20 = *(const bf16x8*)&W2bf[wrow0];
        bf16x8 b21 = *(const bf16x8*)&W2bf[wrow1];
        acc00 = __builtin_amdgcn_mfma_f32_16x16x32_bf16(aU0, b10, acc00, 0, 0, 0);
        acc01 = __builtin_amdgcn_mfma_f32_16x16x32_bf16(aU0, b11, acc01, 0, 0, 0);
        acc10 = __builtin_amdgcn_mfma_f32_16x16x32_bf16(aU1, b10, acc10, 0, 0, 0);
        acc11 = __builtin_amdgcn_mfma_f32_16x16x32_bf16(aU1, b11, acc11, 0, 0, 0);
        acc00 = __builtin_amdgcn_mfma_f32_16x16x32_bf16(aV0, b20, acc00, 0, 0, 0);
        acc01 = __builtin_amdgcn_mfma_f32_16x16x32_bf16(aV0, b21, acc01, 0, 0, 0);
        acc10 = __builtin_amdgcn_mfma_f32_16x16x32_bf16(aV1, b20, acc10, 0, 0, 0);
        acc11 = __builtin_amdgcn_mfma_f32_16x16x32_bf16(aV1, b21, acc11, 0, 0, 0);
    }
    __syncthreads();   // all MFMA reads of Ubf/Vbf done before stage overwrites them
    {
        int c0 = (2 * wv + 0) * 16 + ln16;
        int c1 = (2 * wv + 1) * 16 + ln16;
#pragma unroll
        for (int i = 0; i < 4; i++) {
            int r0 = qd * 4 + i;
            stage[r0 * SSTR + c0] = acc00[i];
            stage[r0 * SSTR + c1] = acc01[i];
            stage[(16 + r0) * SSTR + c0] = acc10[i];
            stage[(16 + r0) * SSTR + c1] = acc11[i];
        }
    }
    __syncthreads();

    float b0v = bias1[lane] + bias2[lane];
    float b1v = bias1[lane + 64] + bias2[lane + 64];
    float lw0 = lnw[lane], lw1 = lnw[lane + 64];
    float lb0 = lnb[lane], lb1 = lnb[lane + 64];
    for (int rr = 0; rr < RROWS / 4; rr++) {
        int r = rr * 4 + wv;
        int row = base + r;
        if (row >= NN) continue;
        float v0 = stage[r * SSTR + lane] + b0v;
        float v1 = stage[r * SSTR + lane + 64] + b1v;
        float s = v0 + v1, s2 = v0 * v0 + v1 * v1;
#pragma unroll
        for (int o2 = 32; o2 > 0; o2 >>= 1) {
            s  += __shfl_xor(s,  o2, 64);
            s2 += __shfl_xor(s2, o2, 64);
        }
        float mu = s * (1.0f / CDIM);
        float var = s2 * (1.0f / CDIM) - mu * mu;
        float rs = rsqrtf(var + 1e-5f);
        float o0 = fmaxf((v0 - mu) * rs * lw0 + lb0, 0.0f);
        float o1 = fmaxf((v1 - mu) * rs * lw1 + lb1, 0.0f);
        size_t oi = (size_t)row * CDIM;
        xnext[oi + lane] = o0;
        xnext[oi + lane + 64] = o1;
        if (xnext_bf) {
            xnext_bf[oi + lane] = f2bf(o0);
            xnext_bf[oi + lane + 64] = f2bf(o1);
        }
    }
}

extern "C" void kernel_launch(void* const* d_in, const int* in_sizes, int n_in,
                              void* d_out, int out_size, void* d_ws, size_t ws_size,
                              hipStream_t stream)
{
    const float* x_a      = (const float*)d_in[0];
    const float* x_b      = (const float*)d_in[1];
    const float* schema_x = (const float*)d_in[2];
    const int*   e_ab     = (const int*)d_in[3];
    const int*   e_ba     = (const int*)d_in[4];
    const int*   e_aa     = (const int*)d_in[5];
    const int*   sei      = (const int*)d_in[6];
    const float* preW     = (const float*)d_in[7];
    const float* preb     = (const float*)d_in[8];
    const float* gcnW     = (const float*)d_in[9];
    const float* gcnb     = (const float*)d_in[10];
    const float* coW      = (const float*)d_in[11];
    const float* cob      = (const float*)d_in[12];
    const float* bases    = (const float*)d_in[13];
    const float* sbias    = (const float*)d_in[14];
    const float* lnw      = (const float*)d_in[15];
    const float* lnb      = (const float*)d_in[16];

    float* out     = (float*)d_out;
    float* out_xa  = out;
    float* out_xb  = out + 6400000;
    float* out_sf  = out + 12800000;
    float* out_ori = out + 12800512;

    float* ws = (float*)d_ws;
    int*      col    = (int*)ws;
    int*      rowptr = (int*)(ws + 2400000);
    unsigned* buf    = (unsigned*)(ws + 2550016);
    int*      bcnt   = (int*)(ws + 4950016);
    int*      boff   = (int*)(ws + 4950320);
    int*      bcur   = (int*)(ws + 4950624);
    float* xa_buf = ws + 4950928;
    float* xb_buf = ws + 11350928;
    unsigned short* Wbf = (unsigned short*)(ws + 17750928);
    float* coeffs = ws + 17800080;
    unsigned short* xa_bf0 = (unsigned short*)(ws + 17800112);
    unsigned short* xb_bf0 = (unsigned short*)(ws + 21000176);
    unsigned short* xa_bf1 = (unsigned short*)(ws + 24200240);
    unsigned short* xb_bf1 = (unsigned short*)(ws + 27400304);

    schema_kernel<<<1, 512, 0, stream>>>(schema_x, sei, preW, preb, gcnW, gcnb,
                                         coW, cob, out_sf, out_ori, coeffs);
    build_w_kernel<<<384, 256, 0, stream>>>(bases, coeffs, Wbf);

    tobf16_kernel<<<(NA * CDIM / 4 + 255) / 256, 256, 0, stream>>>(x_a, xa_bf0, NA * CDIM);
    tobf16_kernel<<<(NB * CDIM / 4 + 255) / 256, 256, 0, stream>>>(x_b, xb_bf0, NB * CDIM);
    zero_rows_kernel<<<1, 256, 0, stream>>>(xa_bf0, xb_bf0, xa_bf1, xb_bf1);

    hipMemsetAsync(bcnt, 0, 3 * NBUCK * sizeof(int), stream);
    dim3 cgrid((EDGES + 4095) / 4096, 3);
    bucket_count_kernel<<<cgrid, 256, 0, stream>>>(e_ab, e_ba, e_aa, bcnt);
    bucket_scan_kernel<<<1, 32, 0, stream>>>(bcnt, boff, bcur);
    bucket_partition_kernel<<<cgrid, 256, 0, stream>>>(e_ab, e_ba, e_aa, bcur, buf);
    dim3 sgrid(NBUCK, 3);
    bucket_scatter_kernel<<<sgrid, 256, 0, stream>>>(buf, boff, rowptr, col);

    const int* rp_ab = rowptr;
    const int* rp_ba = rowptr + (NN + 1);
    const int* rp_aa = rowptr + 2 * (NN + 1);
    const int* col_ab = col;
    const int* col_ba = col + EDGES;
    const int* col_aa = col + 2 * EDGES;

    const int fgrid = (NN + RROWS - 1) / RROWS;   // 1563

    for (int l = 0; l < 2; l++) {
        const float* xa_cur = (l == 0) ? x_a : xa_buf;
        const float* xb_cur = (l == 0) ? x_b : xb_buf;
        const unsigned short* xa_bf = (l == 0) ? xa_bf0 : xa_bf1;
        const unsigned short* xb_bf = (l == 0) ? xb_bf0 : xb_bf1;
        const unsigned short* Wab = Wbf + (size_t)(l * 3 + 0) * 16384;
        const unsigned short* Wba = Wbf + (size_t)(l * 3 + 1) * 16384;
        const unsigned short* Waa = Wbf + (size_t)(l * 3 + 2) * 16384;
        float* xa_nxt = (l == 0) ? xa_buf : out_xa;
        float* xb_nxt = (l == 0) ? xb_buf : out_xb;
        unsigned short* xa_nbf = (l == 0) ? xa_bf1 : nullptr;
        unsigned short* xb_nbf = (l == 0) ? xb_bf1 : nullptr;

        fuse_b_kernel<<<fgrid, 256, 0, stream>>>(
            xa_bf, xb_cur, rp_ab, col_ab, Wab,
            sbias + (size_t)(l * 3 + 0) * 128,
            lnw + (size_t)(l * 2 + 1) * 128, lnb + (size_t)(l * 2 + 1) * 128,
            xb_nxt, xb_nbf);
        fuse_a_kernel<<<fgrid, 256, 0, stream>>>(
            xb_bf, rp_ba, col_ba, xa_bf, rp_aa, col_aa, xa_cur,
            Wba, Waa,
            sbias + (size_t)(l * 3 + 1) * 128, sbias + (size_t)(l * 3 + 2) * 128,
            lnw + (size_t)(l * 2 + 0) * 128, lnb + (size_t)(l * 2 + 0) * 128,
            xa_nxt, xa_nbf);
    }
}